// Round 7
// baseline (457.017 us; speedup 1.0000x reference)
//
#include <hip/hip_runtime.h>
#include <hip/hip_cooperative_groups.h>

namespace cg = cooperative_groups;

// ---------------- workspace layout (indices into uint32/float32 view) -------
// wsu[0] = min key, wsu[1] = max key (monotonic uint mapping of float)
// wsu[2..257] = hist[256]
// wsf[258..514] = edges[257]  (fallback path only)
// wsf[515..518] = vmin/delta/invd/thresh (fallback path only)
// byte offset 4096: gray[npix] (fallback path only)
static constexpr int HIST_OFF   = 2;
static constexpr int EDGES_OFF  = 258;
static constexpr int VMIN_OFF   = 515;
static constexpr int DELTA_OFF  = 516;
static constexpr int INVD_OFF   = 517;
static constexpr int THRESH_OFF = 518;
static constexpr size_t GRAY_BYTE_OFF = 4096;

typedef float nfloat4 __attribute__((ext_vector_type(4)));

__device__ __forceinline__ unsigned fkey(float x) {
    unsigned u = __float_as_uint(x);
    return (u & 0x80000000u) ? ~u : (u | 0x80000000u);
}
__device__ __forceinline__ float keyf(unsigned k) {
    return (k & 0x80000000u) ? __uint_as_float(k & 0x7FFFFFFFu)
                             : __uint_as_float(~k);
}
// gray = ((r*wr + g*wg) + b*wb), strict f32 rounding, NO fma contraction
__device__ __forceinline__ float gray1(float r, float g, float b) {
    float t0 = __fmul_rn(r, 0.2989f);
    float t1 = __fmul_rn(g, 0.5870f);
    float t2 = __fmul_rn(b, 0.1140f);
    return __fadd_rn(__fadd_rn(t0, t1), t2);
}
__device__ __forceinline__ float permf(int dst_addr, float v) {
    return __int_as_float(
        __builtin_amdgcn_ds_permute(dst_addr, __float_as_int(v)));
}
__device__ __forceinline__ float selk(float a, float b, float c, int k) {
    return (k == 0) ? a : ((k == 1) ? b : c);
}
__device__ __forceinline__ unsigned aload(const unsigned* p) {
    return __hip_atomic_load(p, __ATOMIC_RELAXED, __HIP_MEMORY_SCOPE_AGENT);
}

__global__ void init_kernel(unsigned* __restrict__ wsu) {
    int i = threadIdx.x;
    if (i < 256) wsu[HIST_OFF + i] = 0u;
    if (i == 0) { wsu[0] = 0xFFFFFFFFu; wsu[1] = 0u; }
}

// =================== fused cooperative kernel ===============================
// 1024 blocks x 256 thr (4 blocks/CU co-resident). Wave tile = 512 pixel-
// groups (8 rounds of 64); gray kept in 32 VGPRs across all phases.
__global__ void __launch_bounds__(256, 4)
fused_kernel(const float* __restrict__ in, float* __restrict__ out,
             unsigned* __restrict__ wsu, int npix4) {
    cg::grid_group grid = cg::this_grid();
    __shared__ float eds[257];
    __shared__ unsigned lh[256];
    __shared__ float histf[256], centers[256], w2a[256], s2a[256];
    __shared__ unsigned smn[4], smx[4], skey[2];
    __shared__ float sthr;

    const nfloat4* in4 = (const nfloat4*)in;
    nfloat4* out4 = (nfloat4*)out;
    const int lane = threadIdx.x & 63;
    const int gw = (blockIdx.x * blockDim.x + threadIdx.x) >> 6;
    const int gtile = gw * 512;                    // first pixel-group of wave
    const int wbase4 = gw * 1536;                  // first float4 of wave

    // lane-constant exchange maps (see R6 derivation; verified absmax=0)
    const int s3 = lane % 3;
    const int ka = (3 - s3) % 3, kb = (ka + 1) % 3, kc = (ka + 2) % 3;
    const int da = 4 * ((64 * ka + lane) / 3);
    const int db = 4 * ((64 * kb + lane) / 3);
    const int dc = 4 * ((64 * kc + lane) / 3);
    const int ma = lane / 3,         qa = lane % 3;
    const int mb = (64 + lane) / 3,  qb = (64 + lane) % 3;
    const int mc = (128 + lane) / 3, qc = (128 + lane) % 3;

    bool full[8];
#pragma unroll
    for (int r = 0; r < 8; ++r) full[r] = (gtile + r * 64 + 64 <= npix4);

    // ---------- phase 1: gray (registers) + minmax ----------
    float gr[8][4];
    unsigned mn = 0xFFFFFFFFu, mx = 0u;
    nfloat4 cb[2][3];
    if (full[0]) {
#pragma unroll
        for (int k = 0; k < 3; ++k) cb[0][k] = in4[wbase4 + 64 * k + lane];
    }
#pragma unroll
    for (int r = 0; r < 8; ++r) {
        const int cur = r & 1, nxt = cur ^ 1;
        if (r + 1 < 8 && full[r + 1]) {            // prefetch next round
#pragma unroll
            for (int k = 0; k < 3; ++k)
                cb[nxt][k] = in4[wbase4 + (r + 1) * 192 + 64 * k + lane];
        }
        const int gbase = gtile + r * 64;
        nfloat4 d0, d1, d2;
        bool have = false;
        if (full[r]) {
            d0.x = permf(da, selk(cb[cur][0].x, cb[cur][1].x, cb[cur][2].x, ka));
            d0.y = permf(da, selk(cb[cur][0].y, cb[cur][1].y, cb[cur][2].y, ka));
            d0.z = permf(da, selk(cb[cur][0].z, cb[cur][1].z, cb[cur][2].z, ka));
            d0.w = permf(da, selk(cb[cur][0].w, cb[cur][1].w, cb[cur][2].w, ka));
            d1.x = permf(db, selk(cb[cur][0].x, cb[cur][1].x, cb[cur][2].x, kb));
            d1.y = permf(db, selk(cb[cur][0].y, cb[cur][1].y, cb[cur][2].y, kb));
            d1.z = permf(db, selk(cb[cur][0].z, cb[cur][1].z, cb[cur][2].z, kb));
            d1.w = permf(db, selk(cb[cur][0].w, cb[cur][1].w, cb[cur][2].w, kb));
            d2.x = permf(dc, selk(cb[cur][0].x, cb[cur][1].x, cb[cur][2].x, kc));
            d2.y = permf(dc, selk(cb[cur][0].y, cb[cur][1].y, cb[cur][2].y, kc));
            d2.z = permf(dc, selk(cb[cur][0].z, cb[cur][1].z, cb[cur][2].z, kc));
            d2.w = permf(dc, selk(cb[cur][0].w, cb[cur][1].w, cb[cur][2].w, kc));
            have = true;
        } else {
            int g = gbase + lane;
            if (g < npix4) {
                const nfloat4* p = in4 + (size_t)g * 3;
                d0 = p[0]; d1 = p[1]; d2 = p[2];
                have = true;
            }
        }
        if (have) {
            gr[r][0] = gray1(d0.x, d0.y, d0.z);
            gr[r][1] = gray1(d0.w, d1.x, d1.y);
            gr[r][2] = gray1(d1.z, d1.w, d2.x);
            gr[r][3] = gray1(d2.y, d2.z, d2.w);
            unsigned k0 = fkey(gr[r][0]), k1 = fkey(gr[r][1]);
            unsigned k2 = fkey(gr[r][2]), k3 = fkey(gr[r][3]);
            mn = min(mn, min(min(k0, k1), min(k2, k3)));
            mx = max(mx, max(max(k0, k1), max(k2, k3)));
        } else {
            gr[r][0] = gr[r][1] = gr[r][2] = gr[r][3] = 0.0f;
        }
    }
    for (int off = 32; off > 0; off >>= 1) {
        mn = min(mn, (unsigned)__shfl_xor((int)mn, off, 64));
        mx = max(mx, (unsigned)__shfl_xor((int)mx, off, 64));
    }
    {
        int wave = threadIdx.x >> 6;
        if ((threadIdx.x & 63) == 0) { smn[wave] = mn; smx[wave] = mx; }
        __syncthreads();
        if (threadIdx.x == 0) {
            unsigned bmn = min(min(smn[0], smn[1]), min(smn[2], smn[3]));
            unsigned bmx = max(max(smx[0], smx[1]), max(smx[2], smx[3]));
            atomicMin(&wsu[0], bmn);
            atomicMax(&wsu[1], bmx);
        }
    }
    grid.sync();

    // ---------- phase 2: edges (redundant per block, bit-identical) ----------
    if (threadIdx.x == 0) { skey[0] = aload(&wsu[0]); skey[1] = aload(&wsu[1]); }
    __syncthreads();
    const float vmin = keyf(skey[0]);
    const float vmax = keyf(skey[1]);
    const float delta = __fdiv_rn(__fsub_rn(vmax, vmin), 256.0f);
    const float invd = (delta > 0.0f) ? __fdiv_rn(1.0f, delta) : 0.0f;
    if (threadIdx.x < 256)
        eds[threadIdx.x] =
            __fadd_rn(vmin, __fmul_rn((float)threadIdx.x, delta));
    if (threadIdx.x == 0) eds[256] = vmax;
    if (threadIdx.x < 256) lh[threadIdx.x] = 0u;
    __syncthreads();

    // ---------- phase 3: histogram from register grays ----------
#pragma unroll
    for (int r = 0; r < 8; ++r) {
        const int g = gtile + r * 64 + lane;
        if (full[r] || g < npix4) {
#pragma unroll
            for (int j = 0; j < 4; ++j) {
                float x = gr[r][j];
                int b = (int)(__fmul_rn(__fsub_rn(x, vmin), invd));
                b = b < 0 ? 0 : (b > 255 ? 255 : b);
                while (b < 255 && x >= eds[b + 1]) ++b;   // exact searchsorted
                while (b > 0 && x < eds[b]) --b;
                atomicAdd(&lh[b], 1u);
            }
        }
    }
    __syncthreads();
    if (threadIdx.x < 256 && lh[threadIdx.x] != 0u)
        atomicAdd(&wsu[HIST_OFF + threadIdx.x], lh[threadIdx.x]);
    grid.sync();

    // ---------- phase 4: Otsu scan (redundant per block, numpy order) --------
    if (threadIdx.x < 256) {
        float e0 = eds[threadIdx.x], e1 = eds[threadIdx.x + 1];
        centers[threadIdx.x] = __fmul_rn(__fadd_rn(e0, e1), 0.5f);
        histf[threadIdx.x] = (float)aload(&wsu[HIST_OFF + threadIdx.x]);
    }
    __syncthreads();
    if (threadIdx.x == 0) {
        float w = 0.0f, s = 0.0f;
        for (int t = 255; t >= 0; --t) {
            w = __fadd_rn(w, histf[t]);
            s = __fadd_rn(s, __fmul_rn(histf[t], centers[t]));
            w2a[t] = w;
            s2a[t] = s;
        }
        float w1 = 0.0f, s1 = 0.0f, best = -1.0f;
        int bidx = 0;
        for (int t = 0; t < 255; ++t) {
            w1 = __fadd_rn(w1, histf[t]);
            s1 = __fadd_rn(s1, __fmul_rn(histf[t], centers[t]));
            float m1 = __fdiv_rn(s1, fmaxf(w1, 1.0f));
            float m2 = __fdiv_rn(s2a[t + 1], fmaxf(w2a[t + 1], 1.0f));
            float d  = __fsub_rn(m1, m2);
            float v  = __fmul_rn(__fmul_rn(w1, w2a[t + 1]), __fmul_rn(d, d));
            if (v > best) { best = v; bidx = t; }  // first max, like argmax
        }
        sthr = centers[bidx];
    }
    __syncthreads();
    const float thr = sthr;

    // ---------- phase 5: binarize from register grays, unit-stride NT stores -
#pragma unroll
    for (int r = 0; r < 8; ++r) {
        const int gbase = gtile + r * 64;
        if (full[r]) {
            unsigned u = (gr[r][0] > thr ? 1u : 0u) |
                         (gr[r][1] > thr ? 0x100u : 0u) |
                         (gr[r][2] > thr ? 0x10000u : 0u) |
                         (gr[r][3] > thr ? 0x1000000u : 0u);
            const int rb = 3 * gbase;
#pragma unroll
            for (int k = 0; k < 3; ++k) {
                int m = (k == 0) ? ma : (k == 1) ? mb : mc;
                int q = (k == 0) ? qa : (k == 1) ? qb : qc;
                unsigned w = (unsigned)__builtin_amdgcn_ds_bpermute(4 * m,
                                                                    (int)u);
                float h0 = (w & 0xffu)       ? 1.0f : 0.0f;
                float h1 = (w & 0xff00u)     ? 1.0f : 0.0f;
                float h2 = (w & 0xff0000u)   ? 1.0f : 0.0f;
                float h3 = (w & 0xff000000u) ? 1.0f : 0.0f;
                nfloat4 o;
                o.x = (q == 0) ? h0 : (q == 1) ? h1 : h2;
                o.y = (q == 0) ? h0 : (q == 1) ? h1 : h3;
                o.z = (q == 0) ? h0 : (q == 1) ? h2 : h3;
                o.w = (q == 0) ? h1 : (q == 1) ? h2 : h3;
                __builtin_nontemporal_store(o, &out4[rb + 64 * k + lane]);
            }
        } else {
            int t = gbase + lane;
            if (t < npix4) {
                float b0 = (gr[r][0] > thr) ? 1.0f : 0.0f;
                float b1 = (gr[r][1] > thr) ? 1.0f : 0.0f;
                float b2 = (gr[r][2] > thr) ? 1.0f : 0.0f;
                float b3 = (gr[r][3] > thr) ? 1.0f : 0.0f;
                nfloat4* o = out4 + (size_t)t * 3;
                __builtin_nontemporal_store((nfloat4){b0, b0, b0, b1}, &o[0]);
                __builtin_nontemporal_store((nfloat4){b1, b1, b2, b2}, &o[1]);
                __builtin_nontemporal_store((nfloat4){b2, b3, b3, b3}, &o[2]);
            }
        }
    }
}

// =================== fallback path (R6 pipeline, proven) ====================
__global__ void __launch_bounds__(256)
gray_minmax_generic(const float* __restrict__ in, float* __restrict__ gray,
                    unsigned* __restrict__ wsu, int npix4) {
    __shared__ unsigned smn[4], smx[4];
    const float4* in4 = (const float4*)in;
    const int stride = gridDim.x * blockDim.x;
    unsigned mn = 0xFFFFFFFFu, mx = 0u;
    for (int t = blockIdx.x * blockDim.x + threadIdx.x; t < npix4; t += stride) {
        const float4* p = in4 + (size_t)t * 3;
        float4 c0 = p[0], c1 = p[1], c2 = p[2];
        float g0 = gray1(c0.x, c0.y, c0.z);
        float g1 = gray1(c0.w, c1.x, c1.y);
        float g2 = gray1(c1.z, c1.w, c2.x);
        float g3 = gray1(c2.y, c2.z, c2.w);
        if (gray) ((float4*)gray)[t] = make_float4(g0, g1, g2, g3);
        unsigned k0 = fkey(g0), k1 = fkey(g1), k2 = fkey(g2), k3 = fkey(g3);
        mn = min(mn, min(min(k0, k1), min(k2, k3)));
        mx = max(mx, max(max(k0, k1), max(k2, k3)));
    }
    for (int off = 32; off > 0; off >>= 1) {
        mn = min(mn, (unsigned)__shfl_xor((int)mn, off, 64));
        mx = max(mx, (unsigned)__shfl_xor((int)mx, off, 64));
    }
    int wave = threadIdx.x >> 6;
    if ((threadIdx.x & 63) == 0) { smn[wave] = mn; smx[wave] = mx; }
    __syncthreads();
    if (threadIdx.x == 0) {
        mn = min(min(smn[0], smn[1]), min(smn[2], smn[3]));
        mx = max(max(smx[0], smx[1]), max(smx[2], smx[3]));
        atomicMin(&wsu[0], mn);
        atomicMax(&wsu[1], mx);
    }
}

__global__ void edges_kernel(const unsigned* __restrict__ wsu,
                             float* __restrict__ wsf) {
    float vmin = keyf(wsu[0]);
    float vmax = keyf(wsu[1]);
    float delta = __fdiv_rn(__fsub_rn(vmax, vmin), 256.0f);
    int i = threadIdx.x;
    if (i <= 256) {
        float e = (i == 256) ? vmax
                             : __fadd_rn(vmin, __fmul_rn((float)i, delta));
        wsf[EDGES_OFF + i] = e;
    }
    if (i == 0) {
        wsf[VMIN_OFF]  = vmin;
        wsf[DELTA_OFF] = delta;
        wsf[INVD_OFF]  = (delta > 0.0f) ? __fdiv_rn(1.0f, delta) : 0.0f;
    }
}

__device__ __forceinline__ void bin4(float x0, float x1, float x2, float x3,
                                     const float* eds, float vmin, float invd,
                                     unsigned* lh) {
    float xs[4] = {x0, x1, x2, x3};
#pragma unroll
    for (int j = 0; j < 4; ++j) {
        float x = xs[j];
        int b = (int)(__fmul_rn(__fsub_rn(x, vmin), invd));
        b = b < 0 ? 0 : (b > 255 ? 255 : b);
        while (b < 255 && x >= eds[b + 1]) ++b;
        while (b > 0 && x < eds[b]) --b;
        atomicAdd(&lh[b], 1u);
    }
}

__global__ void __launch_bounds__(256)
hist_kernel(const float* __restrict__ gray, const float* __restrict__ in,
            const float* __restrict__ wsf, unsigned* __restrict__ wsu,
            int npix4) {
    __shared__ float eds[257];
    __shared__ unsigned lh[256];
    for (int i = threadIdx.x; i < 257; i += blockDim.x)
        eds[i] = wsf[EDGES_OFF + i];
    if (threadIdx.x < 256) lh[threadIdx.x] = 0u;
    __syncthreads();
    const float vmin = eds[0];
    const float invd = wsf[INVD_OFF];
    const int stride = gridDim.x * blockDim.x;
    for (int t = blockIdx.x * blockDim.x + threadIdx.x; t < npix4; t += stride) {
        float4 g4;
        if (gray) g4 = ((const float4*)gray)[t];
        else {
            const float4* p = (const float4*)in + (size_t)t * 3;
            float4 c0 = p[0], c1 = p[1], c2 = p[2];
            g4 = make_float4(gray1(c0.x, c0.y, c0.z), gray1(c0.w, c1.x, c1.y),
                             gray1(c1.z, c1.w, c2.x), gray1(c2.y, c2.z, c2.w));
        }
        bin4(g4.x, g4.y, g4.z, g4.w, eds, vmin, invd, lh);
    }
    __syncthreads();
    if (threadIdx.x < 256 && lh[threadIdx.x] != 0u)
        atomicAdd(&wsu[HIST_OFF + threadIdx.x], lh[threadIdx.x]);
}

__global__ void otsu_kernel(const unsigned* __restrict__ wsu,
                            float* __restrict__ wsf) {
    __shared__ float histf[256];
    __shared__ float centers[256];
    __shared__ float w2a[256];
    __shared__ float s2a[256];
    int i = threadIdx.x;
    float e0 = wsf[EDGES_OFF + i];
    float e1 = wsf[EDGES_OFF + i + 1];
    centers[i] = __fmul_rn(__fadd_rn(e0, e1), 0.5f);
    histf[i] = (float)wsu[HIST_OFF + i];
    __syncthreads();
    if (i == 0) {
        float w = 0.0f, s = 0.0f;
        for (int t = 255; t >= 0; --t) {
            w = __fadd_rn(w, histf[t]);
            s = __fadd_rn(s, __fmul_rn(histf[t], centers[t]));
            w2a[t] = w;
            s2a[t] = s;
        }
        float w1 = 0.0f, s1 = 0.0f, best = -1.0f;
        int bidx = 0;
        for (int t = 0; t < 255; ++t) {
            w1 = __fadd_rn(w1, histf[t]);
            s1 = __fadd_rn(s1, __fmul_rn(histf[t], centers[t]));
            float m1 = __fdiv_rn(s1, fmaxf(w1, 1.0f));
            float m2 = __fdiv_rn(s2a[t + 1], fmaxf(w2a[t + 1], 1.0f));
            float d  = __fsub_rn(m1, m2);
            float v  = __fmul_rn(__fmul_rn(w1, w2a[t + 1]), __fmul_rn(d, d));
            if (v > best) { best = v; bidx = t; }
        }
        wsf[THRESH_OFF] = centers[bidx];
    }
}

__global__ void __launch_bounds__(256)
binarize_generic(const float* __restrict__ gray, const float* __restrict__ in,
                 const float* __restrict__ wsf, float* __restrict__ out,
                 int npix4) {
    const float thr = wsf[THRESH_OFF];
    const int stride = gridDim.x * blockDim.x;
    nfloat4* out4 = (nfloat4*)out;
    for (int t = blockIdx.x * blockDim.x + threadIdx.x; t < npix4; t += stride) {
        float4 g4;
        if (gray) g4 = ((const float4*)gray)[t];
        else {
            const float4* p = (const float4*)in + (size_t)t * 3;
            float4 c0 = p[0], c1 = p[1], c2 = p[2];
            g4 = make_float4(gray1(c0.x, c0.y, c0.z), gray1(c0.w, c1.x, c1.y),
                             gray1(c1.z, c1.w, c2.x), gray1(c2.y, c2.z, c2.w));
        }
        float b0 = (g4.x > thr) ? 1.0f : 0.0f;
        float b1 = (g4.y > thr) ? 1.0f : 0.0f;
        float b2 = (g4.z > thr) ? 1.0f : 0.0f;
        float b3 = (g4.w > thr) ? 1.0f : 0.0f;
        nfloat4* o = out4 + (size_t)t * 3;
        o[0] = (nfloat4){b0, b0, b0, b1};
        o[1] = (nfloat4){b1, b1, b2, b2};
        o[2] = (nfloat4){b2, b3, b3, b3};
    }
}

extern "C" void kernel_launch(void* const* d_in, const int* in_sizes, int n_in,
                              void* d_out, int out_size, void* d_ws,
                              size_t ws_size, hipStream_t stream) {
    const float* in = (const float*)d_in[0];
    float* out = (float*)d_out;
    int npix  = out_size / 3;
    int npix4 = npix / 4;
    unsigned* wsu = (unsigned*)d_ws;
    float* wsf = (float*)d_ws;

    hipLaunchKernelGGL(init_kernel, dim3(1), dim3(256), 0, stream, wsu);

    void* args[] = {(void*)&in, (void*)&out, (void*)&wsu, (void*)&npix4};
    hipError_t err = hipLaunchCooperativeKernel(
        (const void*)fused_kernel, dim3(1024), dim3(256), args, 0, stream);
    if (err == hipSuccess) return;

    // -------- fallback: proven multi-kernel pipeline --------
    size_t need = GRAY_BYTE_OFF + (size_t)npix * sizeof(float);
    float* gray = (ws_size >= need)
                      ? (float*)((char*)d_ws + GRAY_BYTE_OFF)
                      : nullptr;
    hipLaunchKernelGGL(gray_minmax_generic, dim3(2048), dim3(256), 0, stream,
                       in, gray, wsu, npix4);
    hipLaunchKernelGGL(edges_kernel, dim3(1), dim3(320), 0, stream, wsu, wsf);
    hipLaunchKernelGGL(hist_kernel, dim3(1024), dim3(256), 0, stream,
                       gray, in, wsf, wsu, npix4);
    hipLaunchKernelGGL(otsu_kernel, dim3(1), dim3(256), 0, stream, wsu, wsf);
    hipLaunchKernelGGL(binarize_generic, dim3(2048), dim3(256), 0, stream,
                       gray, in, wsf, out, npix4);
}

// Round 8
// 282.165 us; speedup vs baseline: 1.6197x; 1.6197x over previous
//
#include <hip/hip_runtime.h>

// ---------------- workspace layout (indices into uint32/float32 view) -------
// wsu[0] = min key, wsu[1] = max key (monotonic uint mapping of float)
// wsu[2..257]   = hist[256]
// wsf[258..514] = edges[257]
// wsf[515] = vmin, wsf[516] = delta, wsf[517] = inv_delta, wsf[518] = thresh
// byte offset 4096: gray[npix] (if ws_size permits)
static constexpr int HIST_OFF   = 2;
static constexpr int EDGES_OFF  = 258;
static constexpr int VMIN_OFF   = 515;
static constexpr int DELTA_OFF  = 516;
static constexpr int INVD_OFF   = 517;
static constexpr int THRESH_OFF = 518;
static constexpr size_t GRAY_BYTE_OFF = 4096;

typedef float nfloat4 __attribute__((ext_vector_type(4)));

// async global->LDS DMA, 16 B per lane; LDS dst = wave-uniform base + lane*16
#define GLOAD_LDS16(gp, lp)                                                    \
    __builtin_amdgcn_global_load_lds(                                          \
        (const __attribute__((address_space(1))) void*)(gp),                   \
        (__attribute__((address_space(3))) void*)(lp), 16, 0, 0)

__device__ __forceinline__ unsigned fkey(float x) {
    unsigned u = __float_as_uint(x);
    return (u & 0x80000000u) ? ~u : (u | 0x80000000u);
}
__device__ __forceinline__ float keyf(unsigned k) {
    return (k & 0x80000000u) ? __uint_as_float(k & 0x7FFFFFFFu)
                             : __uint_as_float(~k);
}
// gray = ((r*wr + g*wg) + b*wb), strict f32 rounding, NO fma contraction
__device__ __forceinline__ float gray1(float r, float g, float b) {
    float t0 = __fmul_rn(r, 0.2989f);
    float t1 = __fmul_rn(g, 0.5870f);
    float t2 = __fmul_rn(b, 0.1140f);
    return __fadd_rn(__fadd_rn(t0, t1), t2);
}

__global__ void init_kernel(unsigned* __restrict__ wsu) {
    int i = threadIdx.x;
    if (i < 256) wsu[HIST_OFF + i] = 0u;
    if (i == 0) { wsu[0] = 0xFFFFFFFFu; wsu[1] = 0u; }
}

// ---------- gray pass: async global->LDS DMA, per-wave double buffer --------
// Wave owns 4 tiles of 192 contiguous float4 (=64 pixel-groups each). DMA for
// tile t+1 is in flight while tile t is consumed; loads never occupy wave
// slots (fire-and-forget until s_waitcnt). Buffers are wave-private, so no
// __syncthreads anywhere in the loop. Requires npix4 % 1024 == 0.
__global__ void __launch_bounds__(256)
gray_minmax_async(const float* __restrict__ in, float* __restrict__ gray,
                  unsigned* __restrict__ wsu, int npix4) {
    __shared__ float4 sbuf[4][2][192];            // 4 waves x 2 bufs x 3 KB
    __shared__ unsigned smn[4], smx[4];
    const float4* in4 = (const float4*)in;
    float4* gray4 = (float4*)gray;
    const int lane = threadIdx.x & 63;
    const int w = threadIdx.x >> 6;
    const int gw = blockIdx.x * 4 + w;            // global wave id
    const size_t wbase4 = (size_t)gw * 768;       // wave's first float4
    unsigned mn = 0xFFFFFFFFu, mx = 0u;

    // prime: DMA tile 0 into buffer 0
#pragma unroll
    for (int k = 0; k < 3; ++k)
        GLOAD_LDS16(in4 + wbase4 + 64 * k + lane, &sbuf[w][0][64 * k]);

#pragma unroll
    for (int t = 0; t < 4; ++t) {
        const int cb = t & 1;
        if (t < 3) {
#pragma unroll
            for (int k = 0; k < 3; ++k)
                GLOAD_LDS16(in4 + wbase4 + (size_t)(t + 1) * 192 + 64 * k + lane,
                            &sbuf[w][cb ^ 1][64 * k]);
            // leave only the 3 newest (next tile's DMAs) outstanding:
            // current tile's DMAs + all earlier gray stores have retired.
            __builtin_amdgcn_s_waitcnt(0x0F73);   // vmcnt(3)
        } else {
            __builtin_amdgcn_s_waitcnt(0x0F71);   // vmcnt(1): last DMA done
        }
        float4 c0 = sbuf[w][cb][3 * lane + 0];
        float4 c1 = sbuf[w][cb][3 * lane + 1];
        float4 c2 = sbuf[w][cb][3 * lane + 2];
        float g0 = gray1(c0.x, c0.y, c0.z);
        float g1 = gray1(c0.w, c1.x, c1.y);
        float g2 = gray1(c1.z, c1.w, c2.x);
        float g3 = gray1(c2.y, c2.z, c2.w);
        gray4[(size_t)gw * 256 + t * 64 + lane] = make_float4(g0, g1, g2, g3);
        unsigned k0 = fkey(g0), k1 = fkey(g1), k2 = fkey(g2), k3 = fkey(g3);
        mn = min(mn, min(min(k0, k1), min(k2, k3)));
        mx = max(mx, max(max(k0, k1), max(k2, k3)));
    }
    for (int off = 32; off > 0; off >>= 1) {
        mn = min(mn, (unsigned)__shfl_xor((int)mn, off, 64));
        mx = max(mx, (unsigned)__shfl_xor((int)mx, off, 64));
    }
    if (lane == 0) { smn[w] = mn; smx[w] = mx; }
    __syncthreads();
    if (threadIdx.x == 0) {
        mn = min(min(smn[0], smn[1]), min(smn[2], smn[3]));
        mx = max(max(smx[0], smx[1]), max(smx[2], smx[3]));
        atomicMin(&wsu[0], mn);
        atomicMax(&wsu[1], mx);
    }
}

// generic fallback (R2 shape, proven correct for any size)
__global__ void __launch_bounds__(256)
gray_minmax_generic(const float* __restrict__ in, float* __restrict__ gray,
                    unsigned* __restrict__ wsu, int npix4) {
    __shared__ unsigned smn[4], smx[4];
    const float4* in4 = (const float4*)in;
    const int stride = gridDim.x * blockDim.x;
    unsigned mn = 0xFFFFFFFFu, mx = 0u;
    for (int t = blockIdx.x * blockDim.x + threadIdx.x; t < npix4; t += stride) {
        const float4* p = in4 + (size_t)t * 3;
        float4 c0 = p[0], c1 = p[1], c2 = p[2];
        float g0 = gray1(c0.x, c0.y, c0.z);
        float g1 = gray1(c0.w, c1.x, c1.y);
        float g2 = gray1(c1.z, c1.w, c2.x);
        float g3 = gray1(c2.y, c2.z, c2.w);
        if (gray) ((float4*)gray)[t] = make_float4(g0, g1, g2, g3);
        unsigned k0 = fkey(g0), k1 = fkey(g1), k2 = fkey(g2), k3 = fkey(g3);
        mn = min(mn, min(min(k0, k1), min(k2, k3)));
        mx = max(mx, max(max(k0, k1), max(k2, k3)));
    }
    for (int off = 32; off > 0; off >>= 1) {
        mn = min(mn, (unsigned)__shfl_xor((int)mn, off, 64));
        mx = max(mx, (unsigned)__shfl_xor((int)mx, off, 64));
    }
    int wave = threadIdx.x >> 6;
    if ((threadIdx.x & 63) == 0) { smn[wave] = mn; smx[wave] = mx; }
    __syncthreads();
    if (threadIdx.x == 0) {
        mn = min(min(smn[0], smn[1]), min(smn[2], smn[3]));
        mx = max(max(smx[0], smx[1]), max(smx[2], smx[3]));
        atomicMin(&wsu[0], mn);
        atomicMax(&wsu[1], mx);
    }
}

// replicate jnp.linspace(vmin, vmax, 257) in f32 (see R2-R6, absmax 0)
__global__ void edges_kernel(const unsigned* __restrict__ wsu,
                             float* __restrict__ wsf) {
    float vmin = keyf(wsu[0]);
    float vmax = keyf(wsu[1]);
    float delta = __fdiv_rn(__fsub_rn(vmax, vmin), 256.0f);
    int i = threadIdx.x;
    if (i <= 256) {
        float e = (i == 256) ? vmax
                             : __fadd_rn(vmin, __fmul_rn((float)i, delta));
        wsf[EDGES_OFF + i] = e;
    }
    if (i == 0) {
        wsf[VMIN_OFF]  = vmin;
        wsf[DELTA_OFF] = delta;
        wsf[INVD_OFF]  = (delta > 0.0f) ? __fdiv_rn(1.0f, delta) : 0.0f;
    }
}

__device__ __forceinline__ void bin4(float x0, float x1, float x2, float x3,
                                     const float* eds, float vmin, float invd,
                                     unsigned* lh) {
    float xs[4] = {x0, x1, x2, x3};
#pragma unroll
    for (int j = 0; j < 4; ++j) {
        float x = xs[j];
        int b = (int)(__fmul_rn(__fsub_rn(x, vmin), invd));
        b = b < 0 ? 0 : (b > 255 ? 255 : b);
        while (b < 255 && x >= eds[b + 1]) ++b;   // exact searchsorted fixup
        while (b > 0 && x < eds[b]) --b;
        atomicAdd(&lh[b], 1u);
    }
}

// 8 coalesced gray-float4 loads per thread; per-block LDS hist, one global
// atomicAdd per bin per block.
__global__ void __launch_bounds__(256)
hist_kernel(const float* __restrict__ gray, const float* __restrict__ in,
            const float* __restrict__ wsf, unsigned* __restrict__ wsu,
            int npix4) {
    __shared__ float eds[257];
    __shared__ unsigned lh[256];
    for (int i = threadIdx.x; i < 257; i += blockDim.x)
        eds[i] = wsf[EDGES_OFF + i];
    if (threadIdx.x < 256) lh[threadIdx.x] = 0u;
    __syncthreads();
    const float vmin = eds[0];
    const float invd = wsf[INVD_OFF];
    const int stride = gridDim.x * blockDim.x;
    const int base = blockIdx.x * blockDim.x + threadIdx.x;
    if (gray && base + 7 * stride < npix4) {
        float4 g[8];
#pragma unroll
        for (int j = 0; j < 8; ++j) g[j] = ((const float4*)gray)[base + j * stride];
#pragma unroll
        for (int j = 0; j < 8; ++j)
            bin4(g[j].x, g[j].y, g[j].z, g[j].w, eds, vmin, invd, lh);
    } else {
        for (int t = base; t < npix4; t += stride) {
            float4 g4;
            if (gray) g4 = ((const float4*)gray)[t];
            else {
                const float4* p = (const float4*)in + (size_t)t * 3;
                float4 c0 = p[0], c1 = p[1], c2 = p[2];
                g4 = make_float4(gray1(c0.x, c0.y, c0.z), gray1(c0.w, c1.x, c1.y),
                                 gray1(c1.z, c1.w, c2.x), gray1(c2.y, c2.z, c2.w));
            }
            bin4(g4.x, g4.y, g4.z, g4.w, eds, vmin, invd, lh);
        }
    }
    __syncthreads();
    if (threadIdx.x < 256 && lh[threadIdx.x] != 0u)
        atomicAdd(&wsu[HIST_OFF + threadIdx.x], lh[threadIdx.x]);
}

// sequential f32 Otsu scan on one thread (order-faithful to numpy cumsum)
__global__ void otsu_kernel(const unsigned* __restrict__ wsu,
                            float* __restrict__ wsf) {
    __shared__ float histf[256];
    __shared__ float centers[256];
    __shared__ float w2a[256];
    __shared__ float s2a[256];
    int i = threadIdx.x;
    float e0 = wsf[EDGES_OFF + i];
    float e1 = wsf[EDGES_OFF + i + 1];
    centers[i] = __fmul_rn(__fadd_rn(e0, e1), 0.5f);
    histf[i] = (float)wsu[HIST_OFF + i];
    __syncthreads();
    if (i == 0) {
        float w = 0.0f, s = 0.0f;
        for (int t = 255; t >= 0; --t) {
            w = __fadd_rn(w, histf[t]);
            s = __fadd_rn(s, __fmul_rn(histf[t], centers[t]));
            w2a[t] = w;
            s2a[t] = s;
        }
        float w1 = 0.0f, s1 = 0.0f, best = -1.0f;
        int bidx = 0;
        for (int t = 0; t < 255; ++t) {
            w1 = __fadd_rn(w1, histf[t]);
            s1 = __fadd_rn(s1, __fmul_rn(histf[t], centers[t]));
            float m1 = __fdiv_rn(s1, fmaxf(w1, 1.0f));
            float m2 = __fdiv_rn(s2a[t + 1], fmaxf(w2a[t + 1], 1.0f));
            float d  = __fsub_rn(m1, m2);
            float v  = __fmul_rn(__fmul_rn(w1, w2a[t + 1]), __fmul_rn(d, d));
            if (v > best) { best = v; bidx = t; }  // first max, like argmax
        }
        wsf[THRESH_OFF] = centers[bidx];
    }
}

// binarize: coalesced gray loads, bpermute expand, unit-stride full-line NT
// stores (R6; removed the 2x HBM write amplification)
__global__ void __launch_bounds__(256)
binarize_fast(const float* __restrict__ gray, const float* __restrict__ wsf,
              float* __restrict__ out, int npix4) {
    const float thr = wsf[THRESH_OFF];
    const nfloat4* gray4 = (const nfloat4*)gray;
    nfloat4* out4 = (nfloat4*)out;
    const int lane = threadIdx.x & 63;
    const int gw = (blockIdx.x * blockDim.x + threadIdx.x) >> 6;
    const int ma = lane / 3,         qa = lane % 3;
    const int mb = (64 + lane) / 3,  qb = (64 + lane) % 3;
    const int mc = (128 + lane) / 3, qc = (128 + lane) % 3;

    nfloat4 g[4];
    bool full[4];
#pragma unroll
    for (int r = 0; r < 4; ++r) {
        int gbase = gw * 256 + r * 64;
        full[r] = (gbase + 64 <= npix4);
        if (full[r]) g[r] = gray4[gbase + lane];
    }
#pragma unroll
    for (int r = 0; r < 4; ++r) {
        const int gbase = gw * 256 + r * 64;
        if (full[r]) {
            unsigned u = (g[r].x > thr ? 1u : 0u) |
                         (g[r].y > thr ? 0x100u : 0u) |
                         (g[r].z > thr ? 0x10000u : 0u) |
                         (g[r].w > thr ? 0x1000000u : 0u);
            const int rb = 3 * gbase;
#pragma unroll
            for (int k = 0; k < 3; ++k) {
                int m = (k == 0) ? ma : (k == 1) ? mb : mc;
                int q = (k == 0) ? qa : (k == 1) ? qb : qc;
                unsigned w = (unsigned)__builtin_amdgcn_ds_bpermute(4 * m,
                                                                    (int)u);
                float h0 = (w & 0xffu)       ? 1.0f : 0.0f;
                float h1 = (w & 0xff00u)     ? 1.0f : 0.0f;
                float h2 = (w & 0xff0000u)   ? 1.0f : 0.0f;
                float h3 = (w & 0xff000000u) ? 1.0f : 0.0f;
                nfloat4 o;
                o.x = (q == 0) ? h0 : (q == 1) ? h1 : h2;
                o.y = (q == 0) ? h0 : (q == 1) ? h1 : h3;
                o.z = (q == 0) ? h0 : (q == 1) ? h2 : h3;
                o.w = (q == 0) ? h1 : (q == 1) ? h2 : h3;
                __builtin_nontemporal_store(o, &out4[rb + 64 * k + lane]);
            }
        } else {
            int t = gbase + lane;
            if (t < npix4) {
                nfloat4 gg = gray4[t];
                float b0 = (gg.x > thr) ? 1.0f : 0.0f;
                float b1 = (gg.y > thr) ? 1.0f : 0.0f;
                float b2 = (gg.z > thr) ? 1.0f : 0.0f;
                float b3 = (gg.w > thr) ? 1.0f : 0.0f;
                nfloat4* o = out4 + (size_t)t * 3;
                __builtin_nontemporal_store((nfloat4){b0, b0, b0, b1}, &o[0]);
                __builtin_nontemporal_store((nfloat4){b1, b1, b2, b2}, &o[1]);
                __builtin_nontemporal_store((nfloat4){b2, b3, b3, b3}, &o[2]);
            }
        }
    }
}

__global__ void __launch_bounds__(256)
binarize_generic(const float* __restrict__ gray, const float* __restrict__ in,
                 const float* __restrict__ wsf, float* __restrict__ out,
                 int npix4) {
    const float thr = wsf[THRESH_OFF];
    const int stride = gridDim.x * blockDim.x;
    nfloat4* out4 = (nfloat4*)out;
    for (int t = blockIdx.x * blockDim.x + threadIdx.x; t < npix4; t += stride) {
        float4 g4;
        if (gray) g4 = ((const float4*)gray)[t];
        else {
            const float4* p = (const float4*)in + (size_t)t * 3;
            float4 c0 = p[0], c1 = p[1], c2 = p[2];
            g4 = make_float4(gray1(c0.x, c0.y, c0.z), gray1(c0.w, c1.x, c1.y),
                             gray1(c1.z, c1.w, c2.x), gray1(c2.y, c2.z, c2.w));
        }
        float b0 = (g4.x > thr) ? 1.0f : 0.0f;
        float b1 = (g4.y > thr) ? 1.0f : 0.0f;
        float b2 = (g4.z > thr) ? 1.0f : 0.0f;
        float b3 = (g4.w > thr) ? 1.0f : 0.0f;
        nfloat4* o = out4 + (size_t)t * 3;
        o[0] = (nfloat4){b0, b0, b0, b1};
        o[1] = (nfloat4){b1, b1, b2, b2};
        o[2] = (nfloat4){b2, b3, b3, b3};
    }
}

extern "C" void kernel_launch(void* const* d_in, const int* in_sizes, int n_in,
                              void* d_out, int out_size, void* d_ws,
                              size_t ws_size, hipStream_t stream) {
    const float* in = (const float*)d_in[0];
    float* out = (float*)d_out;
    int npix  = out_size / 3;
    int npix4 = npix / 4;
    unsigned* wsu = (unsigned*)d_ws;
    float* wsf = (float*)d_ws;
    size_t need = GRAY_BYTE_OFF + (size_t)npix * sizeof(float);
    float* gray = (ws_size >= need)
                      ? (float*)((char*)d_ws + GRAY_BYTE_OFF)
                      : nullptr;

    hipLaunchKernelGGL(init_kernel, dim3(1), dim3(256), 0, stream, wsu);
    if (gray && npix4 % 1024 == 0) {
        // async-DMA gray: 1 wave = 4 tiles x 64 groups; block covers 1024
        hipLaunchKernelGGL(gray_minmax_async, dim3(npix4 / 1024), dim3(256), 0,
                           stream, in, gray, wsu, npix4);
    } else {
        hipLaunchKernelGGL(gray_minmax_generic, dim3(2048), dim3(256), 0,
                           stream, in, gray, wsu, npix4);
    }
    hipLaunchKernelGGL(edges_kernel, dim3(1), dim3(320), 0, stream, wsu, wsf);
    hipLaunchKernelGGL(hist_kernel, dim3(1024), dim3(256), 0, stream,
                       gray, in, wsf, wsu, npix4);
    hipLaunchKernelGGL(otsu_kernel, dim3(1), dim3(256), 0, stream, wsu, wsf);
    if (gray) {
        hipLaunchKernelGGL(binarize_fast, dim3((npix4 + 1023) / 1024),
                           dim3(256), 0, stream, gray, wsf, out, npix4);
    } else {
        hipLaunchKernelGGL(binarize_generic, dim3(2048), dim3(256), 0, stream,
                           gray, in, wsf, out, npix4);
    }
}